// Round 5
// baseline (146.562 us; speedup 1.0000x reference)
//
#include <hip/hip_runtime.h>

// x (8,320,320) f32, u (8,12,320,320,2) f32 -> out (8,12,320,320) f32.
//
// R5: back to LDS staging (R4 proved direct global gather is address-
// divergence-bound: ~45us vs 33.5us). Attack the staging redundancy and
// scheduling balance instead:
//  - TILE=40, FPB=6 -> 72x72 f32 tile amortized over 6 frames:
//    staging traffic 76.8MB -> ~20MB; total ~138MB -> ~22us floor.
//  - grid = 8x8x16 = 1024 blocks of 320 thr = EXACTLY 4 blocks/CU, all
//    resident, perfectly balanced (R1's 4800-block grid ran ~4.7 epochs).
//  - 6 frames x 800 px-pairs = 4800 units = 320 thr x 15 iters exactly;
//    unroll 3 keeps 3 independent 16B u-loads in flight per thread.
#define PP 8
#define FF 12
#define MM 320
#define NN 320
#define TILE 40
#define HALO 16
#define LW   (TILE + 2 * HALO)   // 72 staged rows/cols
#define PW   76                  // row stride: 72 data + 4 pad (16B-aligned
                                 // rows, 12-bank skew per row)
#define FPB  6                   // frames per block

typedef float fvec4 __attribute__((ext_vector_type(4)));
typedef float fvec2 __attribute__((ext_vector_type(2)));

__global__ __launch_bounds__(320, 5) void warp_tile_kernel(
    const float* __restrict__ x,
    const float* __restrict__ u,
    float* __restrict__ out)
{
    __shared__ float tile[LW * PW];        // 21,888 B -> 4 blocks/CU = 87.5 KB

    int p  = blockIdx.z >> 1;              // image 0..7
    int f0 = (blockIdx.z & 1) * FPB;       // frame half: 0 or 6
    int i0 = blockIdx.y * TILE;
    int j0 = blockIdx.x * TILE;

    const float* __restrict__ img = x + p * (MM * NN);

    // Stage 72x72 f32 tile (zero outside image). 72*18 = 1296 vec4 groups;
    // 4-col groups are 16B-aligned and fully in or out (all offsets %4==0).
    for (int idx = (int)threadIdx.x; idx < LW * (LW / 4); idx += 320) {
        int r  = idx / 18;
        int c4 = idx - r * 18;
        int gr = i0 - HALO + r;
        int gc = j0 - HALO + c4 * 4;
        fvec4 v = {0.0f, 0.0f, 0.0f, 0.0f};
        if ((unsigned)gr < MM && (unsigned)gc < NN)
            v = *(const fvec4*)(img + gr * NN + gc);
        *(fvec4*)&tile[r * PW + c4 * 4] = v;   // 304B row stride, 16B aligned
    }
    __syncthreads();

    int pf0 = p * FF + f0;

    // 6 frames x (40x40 px = 800 col-pairs) = 4800 units, 15 per thread.
#pragma unroll 3
    for (int it = 0; it < 15; ++it) {
        int idx = (int)threadIdx.x + it * 320;   // 0..4799
        int f   = idx / 800;                     // frame 0..5 (magic mul)
        int pr  = idx - f * 800;                 // pair within tile
        int row = pr / 20;                       // 0..39
        int cp  = pr - row * 20;                 // 0..19
        int gi = i0 + row;
        int gj = j0 + 2 * cp;

        const float* __restrict__ ub = u + (size_t)(pf0 + f) * (MM * NN * 2);
        float* __restrict__ ob = out + (size_t)(pf0 + f) * (MM * NN);

        // One 16B u-load = (dx0,dy0,dx1,dy1) for 2 consecutive pixels.
        fvec4 uv = __builtin_nontemporal_load(
            (const fvec4*)(ub + 2 * ((size_t)gi * NN + gj)));
        float dx[2] = {uv.x, uv.z};
        float dy[2] = {uv.y, uv.w};

        float res[2];
#pragma unroll
        for (int k = 0; k < 2; ++k) {
            float sx = (float)(gj + k) + dx[k];
            float sy = (float)gi + dy[k];
            float fx0 = floorf(sx);
            float fy0 = floorf(sy);
            float wx = sx - fx0;
            float wy = sy - fy0;
            int x0i = (int)fx0;
            int y0i = (int)fy0;

            int lx = x0i - (j0 - HALO);
            int ly = y0i - (i0 - HALO);

            float v00, v01, v10, v11;
            if (((unsigned)lx < (LW - 1)) & ((unsigned)ly < (LW - 1))) {
                // 4 corners = 2x ds_read2_b32 (offset pairs 0/1 and 76/77).
                const float* t = &tile[ly * PW + lx];
                v00 = t[0];
                v01 = t[1];
                v10 = t[PW];
                v11 = t[PW + 1];
            } else {
                // Rare (|flow| >= 16 = 4 sigma): predicated global gather.
                int xc0 = min(max(x0i,     0), NN - 1);
                int xc1 = min(max(x0i + 1, 0), NN - 1);
                int yc0 = min(max(y0i,     0), MM - 1);
                int yc1 = min(max(y0i + 1, 0), MM - 1);
                bool vx0 = (x0i >= 0)     & (x0i < NN);
                bool vx1 = (x0i + 1 >= 0) & (x0i + 1 < NN);
                bool vy0 = (y0i >= 0)     & (y0i < MM);
                bool vy1 = (y0i + 1 >= 0) & (y0i + 1 < MM);
                int r0i = yc0 * NN;
                int r1i = yc1 * NN;
                v00 = (vy0 & vx0) ? img[r0i + xc0] : 0.0f;
                v01 = (vy0 & vx1) ? img[r0i + xc1] : 0.0f;
                v10 = (vy1 & vx0) ? img[r1i + xc0] : 0.0f;
                v11 = (vy1 & vx1) ? img[r1i + xc1] : 0.0f;
            }

            float vt = fmaf(wx, v01 - v00, v00);
            float vb = fmaf(wx, v11 - v10, v10);
            res[k] = fmaf(wy, vb - vt, vt);
        }

        fvec2 o = {res[0], res[1]};
        __builtin_nontemporal_store(o, (fvec2*)(ob + (size_t)gi * NN + gj));
    }
}

extern "C" void kernel_launch(void* const* d_in, const int* in_sizes, int n_in,
                              void* d_out, int out_size, void* d_ws, size_t ws_size,
                              hipStream_t stream) {
    const float* x = (const float*)d_in[0];
    const float* u = (const float*)d_in[1];
    float* out = (float*)d_out;

    dim3 grid(NN / TILE, MM / TILE, PP * (FF / FPB));  // 8 x 8 x 16 = 1024
    dim3 block(320);
    warp_tile_kernel<<<grid, block, 0, stream>>>(x, u, out);
}

// Round 6
// 131.988 us; speedup vs baseline: 1.1104x; 1.1104x over previous
//
#include <hip/hip_runtime.h>

// x (8,320,320) f32, u (8,12,320,320,2) f32 -> out (8,12,320,320) f32.
//
// R6: R1's proven body (TILE=32/HALO=16, 512thr, 4px/thread straight-line,
// f32 LDS staging, line-aligned u/out chunks) with ONE change: 1D grid with
// p = bid & 7 so each XCD (hw round-robin xcd = linear_id % 8) owns exactly
// one image. Each XCD then re-reads only its own 400KB x from its L2 (the 6
// re-stagings of a tile are consecutive bids -> co-resident, miss-merged),
// cutting staging HBM traffic 76.8MB -> ~3.3MB. u loads stay nontemporal to
// keep the stream out of L2. R5's TILE=40 (misaligned chunks, spill-prone
// long loop) regressed to 52us and is abandoned.
#define PP 8
#define FF 12
#define MM 320
#define NN 320
#define TILE 32
#define HALO 16
#define LW   (TILE + 2 * HALO)   // 64 staged rows/cols
#define PW   68                  // row stride: 64 data + 4 pad (16B-aligned
                                 // rows, 4-bank skew per row)
#define FPB  2                   // frames per block

typedef float fvec4 __attribute__((ext_vector_type(4)));
typedef float fvec2 __attribute__((ext_vector_type(2)));

__global__ __launch_bounds__(512, 8) void warp_tile_kernel(
    const float* __restrict__ x,
    const float* __restrict__ u,
    float* __restrict__ out)
{
    __shared__ float tile[LW * PW];        // 17,408 B -> 4 blocks/CU (thread-capped)

    int bid  = blockIdx.x;                 // 0..4799
    int p    = bid & 7;                    // image == XCD (round-robin dispatch)
    int rest = bid >> 3;                   // 0..599
    int fg   = rest % 6;                   // frame-group: consecutive bids of an
    int tid2 = rest / 6;                   // XCD revisit the SAME tile 6x
    int ty   = tid2 / 10;
    int tx   = tid2 - ty * 10;
    int i0   = ty * TILE;
    int j0   = tx * TILE;
    int f0   = fg * FPB;

    const float* __restrict__ img = x + p * (MM * NN);

    // Stage 64x64 f32 tile, zero outside image. Col 4-groups are 16B-aligned
    // and fully in or out. 64*16 = 1024 vec4 groups = 2 iters of 512 threads.
#pragma unroll
    for (int it = 0; it < 2; ++it) {
        int idx = (int)threadIdx.x + it * 512;
        int r  = idx >> 4;                 // 0..63
        int c4 = idx & 15;                 // 0..15
        int gr = i0 - HALO + r;
        int gc = j0 - HALO + c4 * 4;
        fvec4 v = {0.0f, 0.0f, 0.0f, 0.0f};
        if ((unsigned)gr < MM && (unsigned)gc < NN)
            v = *(const fvec4*)(img + gr * NN + gc);
        *(fvec4*)&tile[r * PW + c4 * 4] = v;   // 272B row stride, 16B aligned
    }
    __syncthreads();

    // Thread layout: 2 consecutive cols x 1 row; wave covers 32 cols x 4 rows.
    int tcol = ((int)threadIdx.x & 15) * 2;    // 0..30
    int row0 = ((int)threadIdx.x >> 4);        // 0..31
    int gi = i0 + row0;
    int gj = j0 + tcol;

#pragma unroll
    for (int ff = 0; ff < FPB; ++ff) {
        int pf = p * FF + (f0 + ff);
        const float* __restrict__ ubase = u + (size_t)pf * (MM * NN * 2);
        float* __restrict__ obase = out + (size_t)pf * (MM * NN);

        // 2 pixels/thread/frame: one 16B u-load = (dx0,dy0,dx1,dy1).
        // Nontemporal: u is streamed once; keep L2 for x.
        const fvec4* up = (const fvec4*)(ubase + 2 * ((size_t)gi * NN + gj));
        fvec4 ua = __builtin_nontemporal_load(up);
        float dx[2] = {ua.x, ua.z};
        float dy[2] = {ua.y, ua.w};

        float res[2];
#pragma unroll
        for (int k = 0; k < 2; ++k) {
            float sx = (float)(gj + k) + dx[k];
            float sy = (float)gi + dy[k];
            float fx0 = floorf(sx);
            float fy0 = floorf(sy);
            float wx = sx - fx0;
            float wy = sy - fy0;
            int x0i = (int)fx0;
            int y0i = (int)fy0;

            int lx = x0i - (j0 - HALO);
            int ly = y0i - (i0 - HALO);

            float v00, v01, v10, v11;
            if (((unsigned)lx < (LW - 1)) & ((unsigned)ly < (LW - 1))) {
                // 4 corners = 2x ds_read2_b32 (offset pairs 0/1, 68/69).
                const float* t = &tile[ly * PW + lx];
                v00 = t[0];
                v01 = t[1];
                v10 = t[PW];
                v11 = t[PW + 1];
            } else {
                // Rare (|flow| >= 16 = 4 sigma): predicated global gather
                // (x is L2-resident on this XCD).
                int xc0 = min(max(x0i,     0), NN - 1);
                int xc1 = min(max(x0i + 1, 0), NN - 1);
                int yc0 = min(max(y0i,     0), MM - 1);
                int yc1 = min(max(y0i + 1, 0), MM - 1);
                bool vx0 = (x0i >= 0)     & (x0i < NN);
                bool vx1 = (x0i + 1 >= 0) & (x0i + 1 < NN);
                bool vy0 = (y0i >= 0)     & (y0i < MM);
                bool vy1 = (y0i + 1 >= 0) & (y0i + 1 < MM);
                int r0i = yc0 * NN;
                int r1i = yc1 * NN;
                v00 = (vy0 & vx0) ? img[r0i + xc0] : 0.0f;
                v01 = (vy0 & vx1) ? img[r0i + xc1] : 0.0f;
                v10 = (vy1 & vx0) ? img[r1i + xc0] : 0.0f;
                v11 = (vy1 & vx1) ? img[r1i + xc1] : 0.0f;
            }

            float vt = fmaf(wx, v01 - v00, v00);
            float vb = fmaf(wx, v11 - v10, v10);
            res[k] = fmaf(wy, vb - vt, vt);
        }

        fvec2 o = {res[0], res[1]};
        __builtin_nontemporal_store(o, (fvec2*)(obase + (size_t)gi * NN + gj));
    }
}

extern "C" void kernel_launch(void* const* d_in, const int* in_sizes, int n_in,
                              void* d_out, int out_size, void* d_ws, size_t ws_size,
                              hipStream_t stream) {
    const float* x = (const float*)d_in[0];
    const float* u = (const float*)d_in[1];
    float* out = (float*)d_out;

    dim3 grid(4800);                       // 1D: bid&7 = image = XCD
    dim3 block(512);
    warp_tile_kernel<<<grid, block, 0, stream>>>(x, u, out);
}

// Round 7
// 131.852 us; speedup vs baseline: 1.1116x; 1.0010x over previous
//
#include <hip/hip_runtime.h>

// x (8,320,320) f32, u (8,12,320,320,2) f32 -> out (8,12,320,320) f32.
//
// R7: single-variable change vs the best-known kernel (R1b/R3, ~33.5us):
// FPB 2 -> 12. Each block stages its 64x64 halo'd x-tile ONCE and serves all
// 12 frames, cutting staging HBM traffic 76.8MB -> 12.8MB (the only traffic
// term we can still remove; R3/R6 proved cache-placement tricks are
// neutral). Grid 10x10x8 = 800 blocks, all co-resident -> no epochs.
// Body is byte-identical to R3; frame loop unroll 2 keeps VGPR <= 64
// (launch_bounds(512,8), 4 blocks/CU, LDS 69.6KB/CU).
#define PP 8
#define FF 12
#define MM 320
#define NN 320
#define TILE 32
#define HALO 16
#define LW   (TILE + 2 * HALO)   // 64 staged rows/cols
#define PW   68                  // row stride: 64 data + 4 pad (16B-aligned
                                 // rows, 4-bank skew per row)

typedef float fvec4 __attribute__((ext_vector_type(4)));
typedef float fvec2 __attribute__((ext_vector_type(2)));

__global__ __launch_bounds__(512, 8) void warp_tile_kernel(
    const float* __restrict__ x,
    const float* __restrict__ u,
    float* __restrict__ out)
{
    __shared__ float tile[LW * PW];        // 17,408 B -> 4 blocks/CU (thread-capped)

    int p  = blockIdx.z;                   // image 0..7
    int i0 = blockIdx.y * TILE;
    int j0 = blockIdx.x * TILE;

    const float* __restrict__ img = x + p * (MM * NN);

    // Stage 64x64 f32 tile, zero outside image. Col 4-groups are 16B-aligned
    // and fully in or out. 64*16 = 1024 vec4 groups = 2 iters of 512 threads.
#pragma unroll
    for (int it = 0; it < 2; ++it) {
        int idx = (int)threadIdx.x + it * 512;
        int r  = idx >> 4;                 // 0..63
        int c4 = idx & 15;                 // 0..15
        int gr = i0 - HALO + r;
        int gc = j0 - HALO + c4 * 4;
        fvec4 v = {0.0f, 0.0f, 0.0f, 0.0f};
        if ((unsigned)gr < MM && (unsigned)gc < NN)
            v = *(const fvec4*)(img + gr * NN + gc);
        *(fvec4*)&tile[r * PW + c4 * 4] = v;   // 272B row stride, 16B aligned
    }
    __syncthreads();

    // Thread layout: 2 consecutive cols x 1 row; wave covers 32 cols x 4 rows.
    int tcol = ((int)threadIdx.x & 15) * 2;    // 0..30
    int row0 = ((int)threadIdx.x >> 4);        // 0..31
    int gi = i0 + row0;
    int gj = j0 + tcol;

    // All 12 frames reuse the staged tile. unroll 2: two independent 16B
    // u-loads in flight without blowing the 64-VGPR budget.
#pragma unroll 2
    for (int ff = 0; ff < FF; ++ff) {
        int pf = p * FF + ff;
        const float* __restrict__ ubase = u + (size_t)pf * (MM * NN * 2);
        float* __restrict__ obase = out + (size_t)pf * (MM * NN);

        // 2 pixels/thread/frame: one 16B u-load = (dx0,dy0,dx1,dy1).
        // Nontemporal: u is streamed once; keep L2 for x.
        const fvec4* up = (const fvec4*)(ubase + 2 * ((size_t)gi * NN + gj));
        fvec4 ua = __builtin_nontemporal_load(up);
        float dx[2] = {ua.x, ua.z};
        float dy[2] = {ua.y, ua.w};

        float res[2];
#pragma unroll
        for (int k = 0; k < 2; ++k) {
            float sx = (float)(gj + k) + dx[k];
            float sy = (float)gi + dy[k];
            float fx0 = floorf(sx);
            float fy0 = floorf(sy);
            float wx = sx - fx0;
            float wy = sy - fy0;
            int x0i = (int)fx0;
            int y0i = (int)fy0;

            int lx = x0i - (j0 - HALO);
            int ly = y0i - (i0 - HALO);

            float v00, v01, v10, v11;
            if (((unsigned)lx < (LW - 1)) & ((unsigned)ly < (LW - 1))) {
                // 4 corners = 2x ds_read2_b32 (offset pairs 0/1, 68/69).
                const float* t = &tile[ly * PW + lx];
                v00 = t[0];
                v01 = t[1];
                v10 = t[PW];
                v11 = t[PW + 1];
            } else {
                // Rare (|flow| >= 16 = 4 sigma): predicated global gather.
                int xc0 = min(max(x0i,     0), NN - 1);
                int xc1 = min(max(x0i + 1, 0), NN - 1);
                int yc0 = min(max(y0i,     0), MM - 1);
                int yc1 = min(max(y0i + 1, 0), MM - 1);
                bool vx0 = (x0i >= 0)     & (x0i < NN);
                bool vx1 = (x0i + 1 >= 0) & (x0i + 1 < NN);
                bool vy0 = (y0i >= 0)     & (y0i < MM);
                bool vy1 = (y0i + 1 >= 0) & (y0i + 1 < MM);
                int r0i = yc0 * NN;
                int r1i = yc1 * NN;
                v00 = (vy0 & vx0) ? img[r0i + xc0] : 0.0f;
                v01 = (vy0 & vx1) ? img[r0i + xc1] : 0.0f;
                v10 = (vy1 & vx0) ? img[r1i + xc0] : 0.0f;
                v11 = (vy1 & vx1) ? img[r1i + xc1] : 0.0f;
            }

            float vt = fmaf(wx, v01 - v00, v00);
            float vb = fmaf(wx, v11 - v10, v10);
            res[k] = fmaf(wy, vb - vt, vt);
        }

        fvec2 o = {res[0], res[1]};
        __builtin_nontemporal_store(o, (fvec2*)(obase + (size_t)gi * NN + gj));
    }
}

extern "C" void kernel_launch(void* const* d_in, const int* in_sizes, int n_in,
                              void* d_out, int out_size, void* d_ws, size_t ws_size,
                              hipStream_t stream) {
    const float* x = (const float*)d_in[0];
    const float* u = (const float*)d_in[1];
    float* out = (float*)d_out;

    dim3 grid(NN / TILE, MM / TILE, PP);   // 10 x 10 x 8 = 800 blocks
    dim3 block(512);
    warp_tile_kernel<<<grid, block, 0, stream>>>(x, u, out);
}

// Round 8
// 130.510 us; speedup vs baseline: 1.1230x; 1.0103x over previous
//
#include <hip/hip_runtime.h>

// x (8,320,320) f32, u (8,12,320,320,2) f32 -> out (8,12,320,320) f32.
//
// R8: single-variable ablation vs R7 (FPB=12, 800 blocks, ~36us kernel
// floor insensitive to traffic): replace the nontemporal OUT stores --
// present in EVERY round so far -- with plain stores. Theory: nt-stores
// bypass L2 and retire vmcnt only at HBM (~900cy); the frame loop's
// vmcnt waits for the next u-load then chain on in-flight nt-stores
// (shared counter), exposing HBM write latency every iteration. Plain
// stores retire into L2 (~150cy write-back), unblocking the load stream.
#define PP 8
#define FF 12
#define MM 320
#define NN 320
#define TILE 32
#define HALO 16
#define LW   (TILE + 2 * HALO)   // 64 staged rows/cols
#define PW   68                  // row stride: 64 data + 4 pad (16B-aligned
                                 // rows, 4-bank skew per row)

typedef float fvec4 __attribute__((ext_vector_type(4)));
typedef float fvec2 __attribute__((ext_vector_type(2)));

__global__ __launch_bounds__(512, 8) void warp_tile_kernel(
    const float* __restrict__ x,
    const float* __restrict__ u,
    float* __restrict__ out)
{
    __shared__ float tile[LW * PW];        // 17,408 B -> 4 blocks/CU (thread-capped)

    int p  = blockIdx.z;                   // image 0..7
    int i0 = blockIdx.y * TILE;
    int j0 = blockIdx.x * TILE;

    const float* __restrict__ img = x + p * (MM * NN);

    // Stage 64x64 f32 tile, zero outside image. Col 4-groups are 16B-aligned
    // and fully in or out. 64*16 = 1024 vec4 groups = 2 iters of 512 threads.
#pragma unroll
    for (int it = 0; it < 2; ++it) {
        int idx = (int)threadIdx.x + it * 512;
        int r  = idx >> 4;                 // 0..63
        int c4 = idx & 15;                 // 0..15
        int gr = i0 - HALO + r;
        int gc = j0 - HALO + c4 * 4;
        fvec4 v = {0.0f, 0.0f, 0.0f, 0.0f};
        if ((unsigned)gr < MM && (unsigned)gc < NN)
            v = *(const fvec4*)(img + gr * NN + gc);
        *(fvec4*)&tile[r * PW + c4 * 4] = v;   // 272B row stride, 16B aligned
    }
    __syncthreads();

    // Thread layout: 2 consecutive cols x 1 row; wave covers 32 cols x 4 rows.
    int tcol = ((int)threadIdx.x & 15) * 2;    // 0..30
    int row0 = ((int)threadIdx.x >> 4);        // 0..31
    int gi = i0 + row0;
    int gj = j0 + tcol;

    // All 12 frames reuse the staged tile. unroll 2: two independent 16B
    // u-loads in flight without blowing the 64-VGPR budget.
#pragma unroll 2
    for (int ff = 0; ff < FF; ++ff) {
        int pf = p * FF + ff;
        const float* __restrict__ ubase = u + (size_t)pf * (MM * NN * 2);
        float* __restrict__ obase = out + (size_t)pf * (MM * NN);

        // 2 pixels/thread/frame: one 16B u-load = (dx0,dy0,dx1,dy1).
        // Nontemporal LOAD (proven neutral, keeps L2 for x).
        const fvec4* up = (const fvec4*)(ubase + 2 * ((size_t)gi * NN + gj));
        fvec4 ua = __builtin_nontemporal_load(up);
        float dx[2] = {ua.x, ua.z};
        float dy[2] = {ua.y, ua.w};

        float res[2];
#pragma unroll
        for (int k = 0; k < 2; ++k) {
            float sx = (float)(gj + k) + dx[k];
            float sy = (float)gi + dy[k];
            float fx0 = floorf(sx);
            float fy0 = floorf(sy);
            float wx = sx - fx0;
            float wy = sy - fy0;
            int x0i = (int)fx0;
            int y0i = (int)fy0;

            int lx = x0i - (j0 - HALO);
            int ly = y0i - (i0 - HALO);

            float v00, v01, v10, v11;
            if (((unsigned)lx < (LW - 1)) & ((unsigned)ly < (LW - 1))) {
                // 4 corners = 2x ds_read2_b32 (offset pairs 0/1, 68/69).
                const float* t = &tile[ly * PW + lx];
                v00 = t[0];
                v01 = t[1];
                v10 = t[PW];
                v11 = t[PW + 1];
            } else {
                // Rare (|flow| >= 16 = 4 sigma): predicated global gather.
                int xc0 = min(max(x0i,     0), NN - 1);
                int xc1 = min(max(x0i + 1, 0), NN - 1);
                int yc0 = min(max(y0i,     0), MM - 1);
                int yc1 = min(max(y0i + 1, 0), MM - 1);
                bool vx0 = (x0i >= 0)     & (x0i < NN);
                bool vx1 = (x0i + 1 >= 0) & (x0i + 1 < NN);
                bool vy0 = (y0i >= 0)     & (y0i < MM);
                bool vy1 = (y0i + 1 >= 0) & (y0i + 1 < MM);
                int r0i = yc0 * NN;
                int r1i = yc1 * NN;
                v00 = (vy0 & vx0) ? img[r0i + xc0] : 0.0f;
                v01 = (vy0 & vx1) ? img[r0i + xc1] : 0.0f;
                v10 = (vy1 & vx0) ? img[r1i + xc0] : 0.0f;
                v11 = (vy1 & vx1) ? img[r1i + xc1] : 0.0f;
            }

            float vt = fmaf(wx, v01 - v00, v00);
            float vb = fmaf(wx, v11 - v10, v10);
            res[k] = fmaf(wy, vb - vt, vt);
        }

        // PLAIN store (the single change vs R7): retire into L2 write-back
        // instead of chaining vmcnt on HBM write completion.
        fvec2 o = {res[0], res[1]};
        *(fvec2*)(obase + (size_t)gi * NN + gj) = o;
    }
}

extern "C" void kernel_launch(void* const* d_in, const int* in_sizes, int n_in,
                              void* d_out, int out_size, void* d_ws, size_t ws_size,
                              hipStream_t stream) {
    const float* x = (const float*)d_in[0];
    const float* u = (const float*)d_in[1];
    float* out = (float*)d_out;

    dim3 grid(NN / TILE, MM / TILE, PP);   // 10 x 10 x 8 = 800 blocks
    dim3 block(512);
    warp_tile_kernel<<<grid, block, 0, stream>>>(x, u, out);
}